// Round 1
// baseline (827.895 us; speedup 1.0000x reference)
//
#include <hip/hip_runtime.h>
#include <math.h>

// Choquet tree: B=16 children/node, DEPTH=6, NPAIR=120 (triu k=1), 136 logits/node.
// Per node: m = softmax(theta) ; out = sum(m[:16]*x) + sum(m[16:]*min(x[i],x[j]))
// Implemented unnormalized: (sum w*x + sum w*min) / sum w  with w = exp(theta).

#define BFAC 16
#define NPAIR 120
#define NW 136

__device__ __forceinline__ float choquet_node(const float* __restrict__ ch,
                                              const float* __restrict__ th) {
    const float4* ch4 = reinterpret_cast<const float4*>(ch);
    const float4* th4 = reinterpret_cast<const float4*>(th);
    float x[BFAC];
#pragma unroll
    for (int k = 0; k < 4; ++k) {
        float4 v = ch4[k];
        x[4 * k + 0] = v.x; x[4 * k + 1] = v.y;
        x[4 * k + 2] = v.z; x[4 * k + 3] = v.w;
    }
    float acc0 = 0.f, acc1 = 0.f, den0 = 0.f, den1 = 0.f;
    // singletons: logits 0..15
#pragma unroll
    for (int c = 0; c < 4; ++c) {
        float4 v = th4[c];
        float w0 = __expf(v.x), w1 = __expf(v.y), w2 = __expf(v.z), w3 = __expf(v.w);
        den0 += w0 + w2;
        den1 += w1 + w3;
        acc0 += w0 * x[4 * c + 0] + w2 * x[4 * c + 2];
        acc1 += w1 * x[4 * c + 1] + w3 * x[4 * c + 3];
    }
    // pairs: logits 16..135, triu order (0,1),(0,2)..(0,15),(1,2)..(14,15)
    int p = BFAC;
    float4 v;
#pragma unroll
    for (int i = 0; i < BFAC - 1; ++i) {
#pragma unroll
        for (int j = i + 1; j < BFAC; ++j) {
            int c = p & 3;
            if (c == 0) v = th4[p >> 2];
            float t = (c == 0) ? v.x : (c == 1) ? v.y : (c == 2) ? v.z : v.w;
            float w = __expf(t);
            float mn = fminf(x[i], x[j]);
            if (p & 1) { den1 += w; acc1 += w * mn; }
            else       { den0 += w; acc0 += w * mn; }
            ++p;
        }
    }
    return (acc0 + acc1) / (den0 + den1);
}

// One node per thread; levels 1..3.
__global__ void __launch_bounds__(256)
choquet_level_kernel(const float* __restrict__ in, const float* __restrict__ theta,
                     float* __restrict__ out, int n_nodes) {
    int tid = blockIdx.x * blockDim.x + threadIdx.x;
    if (tid >= n_nodes) return;
    out[tid] = choquet_node(in + (size_t)tid * BFAC, theta + (size_t)tid * NW);
}

// Levels 4(256 nodes) + 5(16) + 6(1) fused in one block via LDS.
__global__ void __launch_bounds__(256)
choquet_tail_kernel(const float* __restrict__ in,
                    const float* __restrict__ th4_,
                    const float* __restrict__ th5_,
                    const float* __restrict__ th6_,
                    float* __restrict__ out) {
    __shared__ __align__(16) float l4[256];
    __shared__ __align__(16) float l5[16];
    int t = threadIdx.x;
    l4[t] = choquet_node(in + (size_t)t * BFAC, th4_ + (size_t)t * NW);
    __syncthreads();
    if (t < 16) l5[t] = choquet_node(l4 + t * BFAC, th5_ + (size_t)t * NW);
    __syncthreads();
    if (t == 0) out[0] = choquet_node(l5, th6_);
}

extern "C" void kernel_launch(void* const* d_in, const int* in_sizes, int n_in,
                              void* d_out, int out_size, void* d_ws, size_t ws_size,
                              hipStream_t stream) {
    const float* x   = (const float*)d_in[0];
    const float* th1 = (const float*)d_in[1];
    const float* th2 = (const float*)d_in[2];
    const float* th3 = (const float*)d_in[3];
    const float* th4 = (const float*)d_in[4];
    const float* th5 = (const float*)d_in[5];
    const float* th6 = (const float*)d_in[6];
    float* out = (float*)d_out;

    // workspace layout (floats): level1 out 1048576 | level2 out 65536 | level3 out 4096
    float* ws0 = (float*)d_ws;
    float* ws1 = ws0 + 1048576;
    float* ws2 = ws1 + 65536;

    // level 1: 16^5 = 1048576 nodes
    choquet_level_kernel<<<4096, 256, 0, stream>>>(x, th1, ws0, 1048576);
    // level 2: 65536 nodes
    choquet_level_kernel<<<256, 256, 0, stream>>>(ws0, th2, ws1, 65536);
    // level 3: 4096 nodes
    choquet_level_kernel<<<16, 256, 0, stream>>>(ws1, th3, ws2, 4096);
    // levels 4..6 fused
    choquet_tail_kernel<<<1, 256, 0, stream>>>(ws2, th4, th5, th6, out);
}